// Round 10
// baseline (140.500 us; speedup 1.0000x reference)
//
#include <hip/hip_runtime.h>
#include <hip/hip_bf16.h>
#include <stdint.h>

typedef __attribute__((ext_vector_type(8))) _Float16 half8_t;
typedef __attribute__((ext_vector_type(4))) _Float16 half4_t;
typedef __attribute__((ext_vector_type(2))) _Float16 half2_t;
typedef __attribute__((ext_vector_type(16))) float f32x16;

#define DIM 64
#define NKH 156             // (i, 16-aligned j-block) groups, K=16 each
#define NSTEP 78            // NKH/2 K=32 steps
#define CH 6                // K-steps staged per phase
#define NPH 13              // NSTEP / CH
#define BM 256              // rows/block; 4 waves x (M=64, N=64)
#define XS_STRIDE 68        // halves
#define WBUF_HALF (CH * 4 * 512)   // 12288 halves = 24 KB per buffer

static_assert(NPH * CH == NSTEP, "phase tiling");

// ---- static pair schedule: for i ascending, j-blocks (i+1)>>4 .. 3 ----
struct SchedT { int i[NKH]; int j0[NKH]; };
constexpr SchedT make_sched() {
    SchedT s{};
    int n = 0;
    for (int i = 0; i < 64; ++i)
        for (int jb = (i + 1) >> 4; jb < 4; ++jb) { s.i[n] = i; s.j0[n] = jb * 16; ++n; }
    return s;
}
constexpr SchedT SC = make_sched();

// runtime copy of the same enumeration (for wpack)
__device__ inline void kg_to_ij(int kg, int& io, int& jo) {
    int cum = 0; io = 0; jo = 0;
    for (int ii = 0; ii < 64; ++ii) {
        int jb0 = (ii + 1) >> 4;
        int nb = 4 - jb0;
        if (kg >= cum && kg < cum + nb) { io = ii; jo = (jb0 + (kg - cum)) * 16; }
        cum += nb;
    }
}

// Pack w1 -> fp16 B-fragments. Chunk c = s*4 + t*2 + h (t = n-tile of 32, h = k-half).
// Element off = (c*64 + lane)*8 + e == id; lane holds B[k=(lane>>5)*8+e][n=t*32+(lane&31)]
// for group kg = s*2 + h, j = j0(kg) + k.
__global__ void wpack_kernel(const float* __restrict__ w1,
                             _Float16* __restrict__ w_h) {
    int id = blockIdx.x * 256 + threadIdx.x;
    if (id >= NSTEP * 4 * 64 * 8) return;
    int e    = id & 7;
    int lane = (id >> 3) & 63;
    int c    = id >> 9;
    int s    = c >> 2;
    int t    = (c >> 1) & 1;
    int h    = c & 1;
    int kg   = s * 2 + h;
    int i, j0;
    kg_to_ij(kg, i, j0);
    int j = j0 + ((lane >> 5) << 3) + e;
    int n = t * 32 + (lane & 31);
    float w = 0.0f;
    if (j > i) {
        int p = i * DIM - (i * (i + 1)) / 2 + (j - i - 1);
        w = w1[p * DIM + n];
    }
    w_h[id] = (_Float16)w;
}

// A-fragment for compile-time group KG, m-tile MT (all register indices static).
template<int KG, int MT>
__device__ __forceinline__ half8_t aprod(const uint32_t (&xr)[2][32], bool hi) {
    constexpr int I  = SC.i[KG];
    constexpr int J0 = SC.j0[KG];
    constexpr int DI = I >> 1;
    constexpr int DJ = J0 >> 1;   // 8-aligned
    uint32_t dwi = hi ? xr[MT][DI ^ 4] : xr[MT][DI];
    half2_t hv = __builtin_bit_cast(half2_t, dwi);
    _Float16 xi = hv[I & 1];
    half2_t xi2 = {xi, xi};
    half8_t r;
    half2_t* rp = reinterpret_cast<half2_t*>(&r);
    #pragma unroll
    for (int e2 = 0; e2 < 4; ++e2) {
        half2_t xj = __builtin_bit_cast(half2_t, xr[MT][DJ + e2]);
        rp[e2] = xi2 * xj;
    }
    return r;
}

// stage one phase: wave w async-copies its 6 chunks (k*4 + w) into buffer `cur`
__device__ __forceinline__ void stage_phase(const _Float16* src_lane,  // w_h + wave*512 + lane*8
                                            _Float16* dst_wave,       // wb  + wave*512
                                            int p, int cur) {
    #pragma unroll
    for (int k = 0; k < CH; ++k)
        __builtin_amdgcn_global_load_lds(
            (const __attribute__((address_space(1))) uint32_t*)(src_lane + (size_t)(p * CH + k) * 2048),
            (__attribute__((address_space(3))) uint32_t*)(dst_wave + cur * WBUF_HALF + k * 2048),
            16, 0, 0);
}

template<int P, int ST>
struct StepT {
    static __device__ __forceinline__ void run(const uint32_t (&xr)[2][32],
                                               f32x16 (&acc)[2][2],
                                               const _Float16* wbc, int lane, bool hi) {
        half8_t bb[4];
        #pragma unroll
        for (int c = 0; c < 4; ++c)
            bb[c] = *reinterpret_cast<const half8_t*>(wbc + (ST * 4 + c) * 512 + lane * 8);

        constexpr int KG0 = (P * CH + ST) * 2;
        half8_t ah0[2], ah1[2];
        ah0[0] = aprod<KG0, 0>(xr, hi);
        ah0[1] = aprod<KG0, 1>(xr, hi);
        ah1[0] = aprod<KG0 + 1, 0>(xr, hi);
        ah1[1] = aprod<KG0 + 1, 1>(xr, hi);

        #pragma unroll
        for (int mt = 0; mt < 2; ++mt)
            #pragma unroll
            for (int nt = 0; nt < 2; ++nt)
                acc[mt][nt] = __builtin_amdgcn_mfma_f32_32x32x16_f16(
                    ah0[mt], bb[nt * 2 + 0], acc[mt][nt], 0, 0, 0);
        #pragma unroll
        for (int mt = 0; mt < 2; ++mt)
            #pragma unroll
            for (int nt = 0; nt < 2; ++nt)
                acc[mt][nt] = __builtin_amdgcn_mfma_f32_32x32x16_f16(
                    ah1[mt], bb[nt * 2 + 1], acc[mt][nt], 0, 0, 0);

        StepT<P, ST + 1>::run(xr, acc, wbc, lane, hi);
    }
};
template<int P>
struct StepT<P, CH> {
    static __device__ __forceinline__ void run(const uint32_t (&)[2][32], f32x16 (&)[2][2],
                                               const _Float16*, int, bool) {}
};

template<int P>
struct Phase {
    static __device__ __forceinline__ void run(const uint32_t (&xr)[2][32],
                                               f32x16 (&acc)[2][2],
                                               const _Float16* src_lane, _Float16* dst_wave,
                                               const _Float16* wb, int lane, bool hi) {
        constexpr int cur = P & 1;
        if constexpr (P + 1 < NPH)
            stage_phase(src_lane, const_cast<_Float16*>(dst_wave) - 0, P + 1, cur ^ 1);
        StepT<P, 0>::run(xr, acc, wb + cur * WBUF_HALF, lane, hi);
        __syncthreads();   // compiler drains vmcnt(0) before s_barrier -> stage landed
        Phase<P + 1>::run(xr, acc, src_lane, dst_wave, wb, lane, hi);
    }
};
template<>
struct Phase<NPH> {
    static __device__ __forceinline__ void run(const uint32_t (&)[2][32], f32x16 (&)[2][2],
                                               const _Float16*, _Float16*, const _Float16*,
                                               int, bool) {}
};

__global__ __launch_bounds__(256, 3)
void prodres_kernel(const float* __restrict__ x,
                    const _Float16* __restrict__ w_h,
                    float* __restrict__ out) {
    // xs (34816 B, dead after register fill) overlaps the w double-buffer (49152 B)
    __shared__ __attribute__((aligned(16))) char smem_raw[2 * WBUF_HALF * 2];
    _Float16* xs = reinterpret_cast<_Float16*>(smem_raw);
    _Float16* wb = reinterpret_cast<_Float16*>(smem_raw);

    const int t    = threadIdx.x;
    const int lane = t & 63;
    const int wave = t >> 6;
    const bool hi  = (lane >> 5) & 1;
    const long brow = (long)blockIdx.x * BM;

    // stage x tile [BM][64] -> xs fp16 (coalesced float4 reads)
    #pragma unroll
    for (int it = 0; it < 16; ++it) {
        int row = it * 16 + (t >> 4);
        int c   = (t & 15) * 4;
        float4 v = *reinterpret_cast<const float4*>(x + (brow + row) * DIM + c);
        half4_t hq;
        hq[0] = (_Float16)v.x; hq[1] = (_Float16)v.y;
        hq[2] = (_Float16)v.z; hq[3] = (_Float16)v.w;
        *reinterpret_cast<half4_t*>(&xs[row * XS_STRIDE + c]) = hq;
    }
    __syncthreads();

    // fill per-lane x registers, XOR-permuted: xr[mt][c] = x_dw[c ^ (hi?4:0)]
    uint32_t xr[2][32];
    #pragma unroll
    for (int mt = 0; mt < 2; ++mt) {
        int row = wave * 64 + mt * 32 + (lane & 31);
        const uint32_t* rp = reinterpret_cast<const uint32_t*>(&xs[row * XS_STRIDE]);
        #pragma unroll
        for (int c2 = 0; c2 < 16; ++c2) {
            int src = (2 * c2) ^ (hi ? 4 : 0);
            uint64_t v = *reinterpret_cast<const uint64_t*>(rp + src);  // ds_read_b64
            xr[mt][2 * c2]     = (uint32_t)v;
            xr[mt][2 * c2 + 1] = (uint32_t)(v >> 32);
        }
    }
    __syncthreads();   // all xs reads done before wb overwrites the same LDS

    f32x16 acc[2][2];
    #pragma unroll
    for (int mt = 0; mt < 2; ++mt)
        #pragma unroll
        for (int nt = 0; nt < 2; ++nt)
            #pragma unroll
            for (int q = 0; q < 16; ++q) acc[mt][nt][q] = 0.0f;

    const _Float16* src_lane = w_h + wave * 512 + lane * 8;
    _Float16* dst_wave = wb + wave * 512;

    // prologue: stage phase 0 into buffer 0
    stage_phase(src_lane, dst_wave, 0, 0);
    __syncthreads();   // vmcnt(0) drain + barrier

    Phase<0>::run(xr, acc, src_lane, dst_wave, wb, lane, hi);

    // epilogue: C/D 32x32 layout col=lane&31, row=(q&3)+8*(q>>2)+4*(lane>>5); fp32 residual
    const int hib = hi ? 4 : 0;
    #pragma unroll
    for (int mt = 0; mt < 2; ++mt)
        #pragma unroll
        for (int q = 0; q < 16; ++q) {
            int rit = (q & 3) + 8 * (q >> 2) + hib;
            long row = brow + wave * 64 + mt * 32 + rit;
            #pragma unroll
            for (int nt = 0; nt < 2; ++nt) {
                int col = nt * 32 + (lane & 31);
                out[row * DIM + col] = acc[mt][nt][q] + x[row * DIM + col];
            }
        }
}

extern "C" void kernel_launch(void* const* d_in, const int* in_sizes, int n_in,
                              void* d_out, int out_size, void* d_ws, size_t ws_size,
                              hipStream_t stream) {
    const float* x  = (const float*)d_in[0];
    const float* w1 = (const float*)d_in[1];
    float* out = (float*)d_out;

    _Float16* w_h = (_Float16*)d_ws;   // NSTEP*4*512 = 159744 halves = 319 KB

    int b_total = in_sizes[0] / DIM;   // 131072

    wpack_kernel<<<(NSTEP * 4 * 64 * 8 + 255) / 256, 256, 0, stream>>>(w1, w_h);
    prodres_kernel<<<b_total / BM, 256, 0, stream>>>(x, w_h, out);
}